// Round 4
// baseline (2024.549 us; speedup 1.0000x reference)
//
#include <hip/hip_runtime.h>
#include <hip/hip_bf16.h>

typedef __hip_bfloat16 bf16;
typedef __attribute__((ext_vector_type(8))) short short8;
typedef __attribute__((ext_vector_type(4))) float f32x4;

#define NN 50000
#define RR 6
#define EE 32768
#define HH 256
#define FF 16
#define NHEAD 8
#define KVP 320   // 272 padded to multiple of 64

struct __align__(8) bf16x4 { bf16 v[4]; };

__device__ __forceinline__ float b2f(bf16 v) { return __bfloat162float(v); }
__device__ __forceinline__ bf16 f2b(float v) { return __float2bfloat16(v); }
__device__ __forceinline__ short f2s(float f) { bf16 b = f2b(f); return __builtin_bit_cast(short, b); }
__device__ __forceinline__ float s2f(short s) { return b2f(__builtin_bit_cast(bf16, s)); }
__device__ __forceinline__ float gelu_f(float x) { return 0.5f * x * (1.0f + erff(x * 0.7071067811865476f)); }
__device__ __forceinline__ unsigned fkey(float f) { unsigned u = __float_as_uint(f); return (u & 0x80000000u) ? ~u : (u | 0x80000000u); }
__device__ __forceinline__ float fdec(unsigned k) { unsigned u = (k & 0x80000000u) ? (k & 0x7fffffffu) : ~k; return __uint_as_float(u); }

// async global->LDS, 16B per lane (dest = wave-uniform base + lane*16)
__device__ __forceinline__ void gl2lds16(const void* g, void* l) {
  __builtin_amdgcn_global_load_lds(
      (const __attribute__((address_space(1))) unsigned int*)g,
      (__attribute__((address_space(3))) unsigned int*)l, 16, 0, 0);
}

// grid-stride zero fill (16B granules)
__global__ void zero_k(uint4* __restrict__ p, int n16)
{
  const uint4 z = make_uint4(0u, 0u, 0u, 0u);
  for (int i = blockIdx.x * blockDim.x + threadIdx.x; i < n16; i += gridDim.x * blockDim.x)
    p[i] = z;
}

// fp32 -> bf16 elementwise (4 per thread)
__global__ void cvt_k(const float* __restrict__ in, bf16* __restrict__ out, int n4)
{
  const int i = blockIdx.x * 256 + threadIdx.x;
  if (i >= n4) return;
  const float4 f = ((const float4*)in)[i];
  bf16x4 o; o.v[0] = f2b(f.x); o.v[1] = f2b(f.y); o.v[2] = f2b(f.z); o.v[3] = f2b(f.w);
  ((bf16x4*)out)[i] = o;
}

// transpose-convert: in fp32 [K][NC] -> out bf16 [NC][Kp], zero-pad K..Kp.
// batch via z with explicit element strides (izs for in, ozs for out).
__global__ void tconv_k(const float* __restrict__ in, bf16* __restrict__ out,
                        int K, int NC, int Kp, long izs, long ozs)
{
  __shared__ float t[32][33];
  in  += (size_t)blockIdx.z * izs;
  out += (size_t)blockIdx.z * ozs;
  const int kb = blockIdx.x * 32, nb = blockIdx.y * 32;
  const int tx = threadIdx.x & 31, ty = threadIdx.x >> 5;  // ty 0..7
  for (int i = ty; i < 32; i += 8) {
    const int k = kb + i, n = nb + tx;
    t[i][tx] = (k < K && n < NC) ? in[(size_t)k * NC + n] : 0.f;
  }
  __syncthreads();
  for (int i = ty; i < 32; i += 8) {
    const int n = nb + i, k = kb + tx;
    if (n < NC && k < Kp) out[(size_t)n * Kp + k] = f2b(t[tx][i]);
  }
}

// build concatenated kv bias: bkv[r][0..255]=bk[r], bkv[r][256..511]=bv[r]
__global__ void bkv_k(const float* __restrict__ bk, const float* __restrict__ bv,
                      float* __restrict__ bkv)
{
  const int i = blockIdx.x * 256 + threadIdx.x;
  if (i >= RR * 512) return;
  const int r = i >> 9, c = i & 511;
  bkv[i] = (c < 256) ? bk[r * 256 + c] : bv[r * 256 + (c - 256)];
}

// copy tmp [N][256] bf16 -> rel_cat slot (ld 1536)
__global__ void copyslot_k(const bf16* __restrict__ tmp, bf16* __restrict__ slot)
{
  const int i = blockIdx.x * 256 + threadIdx.x;  // 8-elem chunk id
  if (i >= NN * 32) return;
  const int n = i >> 5, c = (i & 31) * 8;
  *(short8*)(slot + (size_t)n * 1536 + c) = *(const short8*)(tmp + (size_t)n * 256 + c);
}

// ---------------------------------------------------------------------------
// MFMA GEMM, 2-PHASE double-buffered: C[M,NC] = act(A[M,K] @ Bt^T + bias),
// Bt = [NC][K] bf16 k-contig. 128x128 tile, BK=64, 4 waves, wave = 64x64.
// Per K-step: {issue prefetch of tile t+1 -> compute tile t -> write-late
// reg-staged A -> ONE __syncthreads}. The barrier's vmcnt(0) drain now
// happens AFTER the 32-MFMA compute phase, hiding most of the HBM latency
// (T3-minimal + T14 issue-early/write-late; 1-phase exposed it fully).
// LDS chunk (row, cg) holds global chunk cg ^ (row&7): staging stays
// lane-contiguous (gl2lds16-legal) while fragment reads spread banks.
// ASRC: 0=A bf16 async (gl2lds); 1=A fp32 reg-staged (convert at write);
//       2=PAIR bf16 sum reg-staged; 3=KV gather reg-staged
//       (xb[src[r]] bf16 | eab bf16 | zero pad), src hoisted.
// ZMODE: 0=plain; 1=logits: A = rel_cat + slot3[z]*256, epilogue
//        atomicAdd(logits[z*M+row], sum_col tanh(c+bias[col])*wa2[col]);
//        3=metapath batch: z=blockIdx.z+z0 picks pair slots r1/r2 + B/bias,
//        C += blockIdx.z*M*256 (contiguous tmp; in-place slot writes unsafe).
// ---------------------------------------------------------------------------
template<int ASRC, int ACT, int ZMODE, typename TO>
__global__ __launch_bounds__(256) void mm_k(
    const void* __restrict__ Av, const bf16* __restrict__ A2, int lda,
    const int* __restrict__ src, const bf16* __restrict__ eab,
    const bf16* __restrict__ Bt, const float* __restrict__ bias,
    const float* __restrict__ wa2, TO* __restrict__ C, int ldc,
    float* __restrict__ logits, int M, int K, int z0)
{
  __shared__ short lA[2][128 * 64];
  __shared__ short lB[2][128 * 64];
  const int tid = threadIdx.x;
  const int w = tid >> 6, l = tid & 63;
  const int col0 = blockIdx.x << 7;
  const int row0 = blockIdx.y << 7;
  const bf16* Ab = (const bf16*)Av;
  const float* Af = (const float*)Av;
  const bf16* A2b = A2;
  const bf16* Btz = Bt;
  const float* biasz = bias;
  TO* Cz = C;
  float* lg = logits;
  if constexpr (ZMODE == 1) {
    const int slots3[3] = {2, 4, 1};
    Ab = (const bf16*)Av + slots3[blockIdx.z] * 256;
    lg = logits + (size_t)blockIdx.z * M;
  } else if constexpr (ZMODE == 3) {
    const int r1s[3] = {2, 4, 1}, r2s[3] = {3, 0, 5};
    const int z = blockIdx.z + z0;
    Ab  = (const bf16*)Av + (size_t)r1s[z] * 256;
    A2b = A2 + (size_t)r2s[z] * 256;
    Btz = Bt + (size_t)z * 256 * K;
    biasz = bias + z * 256;
    Cz = C + (size_t)blockIdx.z * (size_t)M * 256;
  }
  const int wm = (w >> 1) << 6, wn = (w & 1) << 6;
  const int lane15 = l & 15, kq = l >> 4;

  // loop-invariant staging geometry (idx = 16B chunk id 0..1023)
  int idx8[4], rowi[4], scg8[4], ri[4], si[4];
#pragma unroll
  for (int i = 0; i < 4; ++i) {
    const int idx = (w * 4 + i) * 64 + l;
    rowi[i] = idx >> 3;
    scg8[i] = ((idx & 7) ^ (rowi[i] & 7)) * 8;   // swizzled k-offset (elems)
    idx8[i] = idx * 8;
    ri[i]   = min(row0 + rowi[i], M - 1);
    if constexpr (ASRC == 3) si[i] = src[ri[i]];
  }

  f32x4 acc[4][4] = {};
  const int NT = K >> 6;

  // ---- prologue: stage tile 0 fully into buf 0 ----
  {
    short8 ps[4], ps2[4]; float4 pf[8];
#pragma unroll
    for (int i = 0; i < 4; ++i) {
      const int kc = scg8[i];
      gl2lds16(Btz + (size_t)(col0 + rowi[i]) * K + kc, &lB[0][idx8[i]]);
      if constexpr (ASRC == 0) {
        gl2lds16(Ab + (size_t)ri[i] * lda + kc, &lA[0][idx8[i]]);
      } else if constexpr (ASRC == 1) {
        const float* p = Af + (size_t)ri[i] * lda + kc;
        pf[2 * i] = *(const float4*)p; pf[2 * i + 1] = *(const float4*)(p + 4);
      } else if constexpr (ASRC == 2) {
        ps[i]  = *(const short8*)(Ab  + (size_t)ri[i] * lda + kc);
        ps2[i] = *(const short8*)(A2b + (size_t)ri[i] * lda + kc);
      } else {
        if (kc < HH) ps[i] = *(const short8*)(Ab + (size_t)si[i] * HH + kc);
        else if (kc < HH + FF) ps[i] = *(const short8*)(eab + (size_t)ri[i] * FF + (kc - HH));
        else { short8 z; for (int j = 0; j < 8; ++j) z[j] = 0; ps[i] = z; }
      }
    }
    if constexpr (ASRC == 1) {
#pragma unroll
      for (int i = 0; i < 4; ++i) {
        short8 s;
        s[0] = f2s(pf[2*i].x); s[1] = f2s(pf[2*i].y); s[2] = f2s(pf[2*i].z); s[3] = f2s(pf[2*i].w);
        s[4] = f2s(pf[2*i+1].x); s[5] = f2s(pf[2*i+1].y); s[6] = f2s(pf[2*i+1].z); s[7] = f2s(pf[2*i+1].w);
        *(short8*)&lA[0][idx8[i]] = s;
      }
    } else if constexpr (ASRC == 2) {
#pragma unroll
      for (int i = 0; i < 4; ++i) {
        short8 s;
#pragma unroll
        for (int j = 0; j < 8; ++j) s[j] = f2s(s2f(ps[i][j]) + s2f(ps2[i][j]));
        *(short8*)&lA[0][idx8[i]] = s;
      }
    } else if constexpr (ASRC == 3) {
#pragma unroll
      for (int i = 0; i < 4; ++i) *(short8*)&lA[0][idx8[i]] = ps[i];
    }
  }
  __syncthreads();

  int cur = 0;
  for (int t = 0; t < NT; ++t) {
    const int nb = cur ^ 1;
    const bool pfch = (t + 1 < NT);
    short8 ps[4], ps2[4]; float4 pf[8];
    // ---- issue prefetch of tile t+1 ----
    if (pfch) {
      const int k0n = (t + 1) << 6;
#pragma unroll
      for (int i = 0; i < 4; ++i) {
        const int kc = k0n + scg8[i];
        gl2lds16(Btz + (size_t)(col0 + rowi[i]) * K + kc, &lB[nb][idx8[i]]);
        if constexpr (ASRC == 0) {
          gl2lds16(Ab + (size_t)ri[i] * lda + kc, &lA[nb][idx8[i]]);
        } else if constexpr (ASRC == 1) {
          const float* p = Af + (size_t)ri[i] * lda + kc;
          pf[2 * i] = *(const float4*)p; pf[2 * i + 1] = *(const float4*)(p + 4);
        } else if constexpr (ASRC == 2) {
          ps[i]  = *(const short8*)(Ab  + (size_t)ri[i] * lda + kc);
          ps2[i] = *(const short8*)(A2b + (size_t)ri[i] * lda + kc);
        } else {
          if (kc < HH) ps[i] = *(const short8*)(Ab + (size_t)si[i] * HH + kc);
          else if (kc < HH + FF) ps[i] = *(const short8*)(eab + (size_t)ri[i] * FF + (kc - HH));
          else { short8 z; for (int j = 0; j < 8; ++j) z[j] = 0; ps[i] = z; }
        }
      }
    }
    // ---- compute on buf cur ----
#pragma unroll
    for (int kk = 0; kk < 64; kk += 32) {
      short8 af[4], bfr[4];
#pragma unroll
      for (int tt = 0; tt < 4; ++tt) {
        const int ra = wm + tt * 16 + lane15;
        const int ca = ((kk >> 3) + kq) ^ (ra & 7);
        af[tt] = *(const short8*)&lA[cur][ra * 64 + ca * 8];
        const int rb = wn + tt * 16 + lane15;
        const int cb = ((kk >> 3) + kq) ^ (rb & 7);
        bfr[tt] = *(const short8*)&lB[cur][rb * 64 + cb * 8];
      }
#pragma unroll
      for (int ti = 0; ti < 4; ++ti)
#pragma unroll
        for (int tj = 0; tj < 4; ++tj)
          acc[ti][tj] = __builtin_amdgcn_mfma_f32_16x16x32_bf16(af[ti], bfr[tj], acc[ti][tj], 0, 0, 0);
    }
    // ---- write-late: reg-staged A -> lds[nb] (vmcnt waits land here) ----
    if (pfch) {
      if constexpr (ASRC == 1) {
#pragma unroll
        for (int i = 0; i < 4; ++i) {
          short8 s;
          s[0] = f2s(pf[2*i].x); s[1] = f2s(pf[2*i].y); s[2] = f2s(pf[2*i].z); s[3] = f2s(pf[2*i].w);
          s[4] = f2s(pf[2*i+1].x); s[5] = f2s(pf[2*i+1].y); s[6] = f2s(pf[2*i+1].z); s[7] = f2s(pf[2*i+1].w);
          *(short8*)&lA[nb][idx8[i]] = s;
        }
      } else if constexpr (ASRC == 2) {
#pragma unroll
        for (int i = 0; i < 4; ++i) {
          short8 s;
#pragma unroll
          for (int j = 0; j < 8; ++j) s[j] = f2s(s2f(ps[i][j]) + s2f(ps2[i][j]));
          *(short8*)&lA[nb][idx8[i]] = s;
        }
      } else if constexpr (ASRC == 3) {
#pragma unroll
        for (int i = 0; i < 4; ++i) *(short8*)&lA[nb][idx8[i]] = ps[i];
      }
    }
    __syncthreads();
    cur = nb;
  }

  if constexpr (ZMODE != 1) {
    // C layout: col = lane&15, row = (lane>>4)*4 + reg  [m89-verified]
#pragma unroll
    for (int ti = 0; ti < 4; ++ti) {
#pragma unroll
      for (int reg = 0; reg < 4; ++reg) {
        const int row = row0 + wm + ti * 16 + kq * 4 + reg;
        if (row >= M) continue;
#pragma unroll
        for (int tj = 0; tj < 4; ++tj) {
          const int col = col0 + wn + tj * 16 + lane15;
          float v = acc[ti][tj][reg] + biasz[col];
          if constexpr (ACT == 1) v = gelu_f(v);
          if constexpr (sizeof(TO) == 2) Cz[(size_t)row * ldc + col] = (TO)f2b(v);
          else                           Cz[(size_t)row * ldc + col] = (TO)v;
        }
      }
    }
  } else {
#pragma unroll
    for (int ti = 0; ti < 4; ++ti) {
#pragma unroll
      for (int reg = 0; reg < 4; ++reg) {
        float part = 0.f;
#pragma unroll
        for (int tj = 0; tj < 4; ++tj) {
          const int col = col0 + wn + tj * 16 + lane15;
          part += tanhf(acc[ti][tj][reg] + biasz[col]) * wa2[col];
        }
#pragma unroll
        for (int off = 8; off > 0; off >>= 1) part += __shfl_xor(part, off, 64);
        const int row = row0 + wm + ti * 16 + kq * 4 + reg;
        if (lane15 == 0 && row < M) atomicAdd(&lg[row], part);
      }
    }
  }
}

// ---------------------------------------------------------------------------
// Edge-side kernels; q lives in rel_cat (ld 1536, slot r), k/v in kv [E][512]
// Wave-per-edge: 4 edges/block, lane l covers elems l*4..l*4+3, head = l>>3.
// ---------------------------------------------------------------------------
__global__ void scores_k(const bf16* __restrict__ q, const bf16* __restrict__ kv,
                         const int* __restrict__ dst_idx, const float* __restrict__ prior_r,
                         float* __restrict__ scores, unsigned* __restrict__ mkey)
{
  const int wv = threadIdx.x >> 6, l = threadIdx.x & 63;
  const int e = blockIdx.x * 4 + wv;
  const int dst = dst_idx[e];
  const bf16x4 qv = *(const bf16x4*)(q  + (size_t)dst * 1536 + l * 4);
  const bf16x4 kq = *(const bf16x4*)(kv + (size_t)e * 512 + l * 4);
  float p = b2f(qv.v[0]) * b2f(kq.v[0]) + b2f(qv.v[1]) * b2f(kq.v[1])
          + b2f(qv.v[2]) * b2f(kq.v[2]) + b2f(qv.v[3]) * b2f(kq.v[3]);
#pragma unroll
  for (int off = 4; off > 0; off >>= 1) p += __shfl_down(p, off, 8);
  if ((l & 7) == 0) {
    const int h = l >> 3;
    const float s = p * 0.1767766952966369f * prior_r[h];
    scores[e * NHEAD + h] = s;
    atomicMax(&mkey[dst * NHEAD + h], fkey(s));
  }
}

__global__ void expden_k(const float* __restrict__ scores, const int* __restrict__ dst_idx,
                         const unsigned* __restrict__ mkey, float* __restrict__ ex,
                         float* __restrict__ denom)
{
  const int idx = blockIdx.x * 256 + threadIdx.x;
  if (idx >= EE * NHEAD) return;
  const int e = idx >> 3, h = idx & 7;
  const int dst = dst_idx[e];
  const float m = fdec(mkey[dst * NHEAD + h]);
  const float v = expf(scores[idx] - m);
  ex[idx] = v;
  atomicAdd(&denom[dst * NHEAD + h], v);
}

__global__ void agg_k(const float* __restrict__ ex, const float* __restrict__ denom,
                      const bf16* __restrict__ kv, const int* __restrict__ dst_idx,
                      float* __restrict__ agg)
{
  const int wv = threadIdx.x >> 6, l = threadIdx.x & 63;
  const int e = blockIdx.x * 4 + wv;
  const int dst = dst_idx[e];
  const int h = l >> 3;
  const float w = ex[e * NHEAD + h] / (denom[dst * NHEAD + h] + 1e-16f);
  const bf16x4 vv = *(const bf16x4*)(kv + (size_t)e * 512 + 256 + l * 4);
  float* ap = agg + (size_t)dst * HH + l * 4;
#pragma unroll
  for (int j = 0; j < 4; ++j) atomicAdd(ap + j, w * b2f(vv.v[j]));
}

// ---------------------------------------------------------------------------
// inter-relation softmax weights; one wave per node
// ---------------------------------------------------------------------------
__global__ void interw_k(const bf16* __restrict__ h, const float* __restrict__ W2,
                         const float* __restrict__ b2, float* __restrict__ interw)
{
  const int wv = threadIdx.x >> 6, ln = threadIdx.x & 63;
  const int n = blockIdx.x * 4 + wv;
  if (n >= NN) return;
  float a[6] = {0.f, 0.f, 0.f, 0.f, 0.f, 0.f};
#pragma unroll
  for (int kq = 0; kq < 4; ++kq) {
    const int k = ln + (kq << 6);
    const float hv = b2f(h[(size_t)n * HH + k]);
#pragma unroll
    for (int j = 0; j < 6; ++j) a[j] += hv * W2[k * 6 + j];
  }
#pragma unroll
  for (int j = 0; j < 6; ++j) {
#pragma unroll
    for (int off = 32; off > 0; off >>= 1) a[j] += __shfl_down(a[j], off, 64);
  }
  if (ln == 0) {
    float lg[6], e[6], mx = -1e30f, s = 0.f;
#pragma unroll
    for (int j = 0; j < 6; ++j) { lg[j] = a[j] + b2[j]; mx = fmaxf(mx, lg[j]); }
#pragma unroll
    for (int j = 0; j < 6; ++j) { e[j] = expf(lg[j] - mx); s += e[j]; }
    const float inv = 1.0f / s;
#pragma unroll
    for (int j = 0; j < 6; ++j) interw[(size_t)n * 6 + j] = e[j] * inv;
  }
}

// rel_cat layout: [N][R*256]
__global__ void interagg_k(const float* __restrict__ interw, const bf16* __restrict__ rel_cat,
                           bf16* __restrict__ comb)
{
  const int n = blockIdx.x, t = threadIdx.x;
  float acc = 0.f;
#pragma unroll
  for (int r = 0; r < 6; ++r)
    acc += interw[(size_t)n * 6 + r] * b2f(rel_cat[(size_t)n * 1536 + r * 256 + t]);
  comb[(size_t)n * 512 + t] = f2b(acc);
}

// ---------------------------------------------------------------------------
// meta final: softmax(logits[3]) -> weighted sum of stacked -> LN -> comb[:,256:]
// stacked[p] lives in rel_cat slots {2,4,1} (ld 1536); logits = [3][N] fp32
// ---------------------------------------------------------------------------
__global__ void metafinal_k(const float* __restrict__ logits, const bf16* __restrict__ rel_cat,
                            const float* __restrict__ gmeta, const float* __restrict__ bmeta,
                            bf16* __restrict__ comb)
{
  const int wv = threadIdx.x >> 6, ln = threadIdx.x & 63;
  const int n = blockIdx.x * 4 + wv;
  if (n >= NN) return;
  const float l0 = logits[n], l1 = logits[NN + n], l2 = logits[2 * NN + n];
  const float mx = fmaxf(l0, fmaxf(l1, l2));
  const float e0 = expf(l0 - mx), e1 = expf(l1 - mx), e2 = expf(l2 - mx);
  const float inv = 1.0f / (e0 + e1 + e2);
  const float a0 = e0 * inv, a1 = e1 * inv, a2 = e2 * inv;
  const size_t base = (size_t)n * 1536;
  float pre[4], s = 0.f, s2 = 0.f;
#pragma unroll
  for (int q4 = 0; q4 < 4; ++q4) {
    const int j = ln + (q4 << 6);
    const float v = a0 * b2f(rel_cat[base + 2 * 256 + j])
                  + a1 * b2f(rel_cat[base + 4 * 256 + j])
                  + a2 * b2f(rel_cat[base + 1 * 256 + j]);
    pre[q4] = v; s += v; s2 += v * v;
  }
#pragma unroll
  for (int off = 32; off > 0; off >>= 1) { s += __shfl_down(s, off, 64); s2 += __shfl_down(s2, off, 64); }
  s = __shfl(s, 0, 64); s2 = __shfl(s2, 0, 64);
  const float mu = s * (1.0f / 256.0f);
  const float var = s2 * (1.0f / 256.0f) - mu * mu;
  const float rs = rsqrtf(var + 1e-5f);
#pragma unroll
  for (int q4 = 0; q4 < 4; ++q4) {
    const int j = ln + (q4 << 6);
    comb[(size_t)n * 512 + 256 + j] = f2b((pre[q4] - mu) * rs * gmeta[j] + bmeta[j]);
  }
}

// final: out = LN(x + combined)
__global__ void final_k(const float* __restrict__ x, const float* __restrict__ combined,
                        const float* __restrict__ g, const float* __restrict__ b,
                        float* __restrict__ out)
{
  __shared__ float sred[8];
  const int n = blockIdx.x, t = threadIdx.x;
  const float v = x[(size_t)n * HH + t] + combined[(size_t)n * HH + t];
  float s = v, s2 = v * v;
#pragma unroll
  for (int off = 32; off > 0; off >>= 1) { s += __shfl_down(s, off, 64); s2 += __shfl_down(s2, off, 64); }
  const int wv = t >> 6;
  if ((t & 63) == 0) { sred[wv] = s; sred[4 + wv] = s2; }
  __syncthreads();
  const float st = sred[0] + sred[1] + sred[2] + sred[3];
  const float st2 = sred[4] + sred[5] + sred[6] + sred[7];
  const float mu = st * (1.0f / 256.0f);
  const float var = st2 * (1.0f / 256.0f) - mu * mu;
  const float rs = rsqrtf(var + 1e-5f);
  out[(size_t)n * HH + t] = (v - mu) * rs * g[t] + b[t];
}

// ---------------------------------------------------------------------------
extern "C" void kernel_launch(void* const* d_in, const int* in_sizes, int n_in,
                              void* d_out, int out_size, void* d_ws, size_t ws_size,
                              hipStream_t stream)
{
  const float* x      = (const float*)d_in[0];
  const int*   eidx   = (const int*)d_in[1];
  const float* eattr  = (const float*)d_in[2];
  const float* Wq     = (const float*)d_in[3];
  const float* bq     = (const float*)d_in[4];
  const float* Wk     = (const float*)d_in[5];
  const float* bk     = (const float*)d_in[6];
  const float* Wv     = (const float*)d_in[7];
  const float* bv     = (const float*)d_in[8];
  const float* prior  = (const float*)d_in[9];
  const float* Wm     = (const float*)d_in[10];
  const float* bm     = (const float*)d_in[11];
  const float* W_ir1  = (const float*)d_in[12];
  const float* b_ir1  = (const float*)d_in[13];
  const float* W_ir2  = (const float*)d_in[14];
  const float* b_ir2  = (const float*)d_in[15];
  const float* Wmp    = (const float*)d_in[16];
  const float* bmp    = (const float*)d_in[17];
  const float* Wa1    = (const float*)d_in[18];
  const float* ba1    = (const float*)d_in[19];
  const float* Wa2    = (const float*)d_in[20];
  const float* g_meta = (const float*)d_in[21];
  const float* b_meta = (const float*)d_in[22];
  const float* Wc     = (const float*)d_in[23];
  const float* bc     = (const float*)d_in[24];
  const float* g_out  = (const float*)d_in[25];
  const float* b_out  = (const float*)d_in[26];
  float* out = (float*)d_out;

  // ---- workspace layout: PEAK ~229.4 MB (< 235.88 MB proven safe) ----
  char* ws = (char*)d_ws;
  bf16* rel_cat = (bf16*)ws;                         // [N][1536] bf16 = 153,600,000
  char* W0 = ws + 153600000;                         // weights: 5,058,560
  bf16*  Wqt   = (bf16*)(W0 + 0);          // [1536][256]   (6 relations stacked on NC)
  bf16*  Wkvt  = (bf16*)(W0 + 786432);     // [6][512][320] (k rows 0..255, v rows 256..511)
  bf16*  Wmt   = (bf16*)(W0 + 2752512);    // [6][256][256]
  bf16*  Wir1t = (bf16*)(W0 + 3538944);    // [256][1536]
  bf16*  Wct   = (bf16*)(W0 + 4325376);    // [256][512]
  bf16*  Wmpt  = (bf16*)(W0 + 4587520);    // [3][256][256]
  bf16*  Wa1t  = (bf16*)(W0 + 4980736);    // [128][256]
  float* bkv   = (float*)(W0 + 5046272);   // [6][512] fp32 (end 5,058,560)
  char* region = ws + 158658560;
  // phase-1 views
  bf16*     kvbuf = (bf16*)(region + 0);             // [E][512] bf16 = 33,554,432
  float*    sc    = (float*)(region + 33554432);     //  1,048,576
  float*    exb   = (float*)(region + 34603008);     //  1,048,576
  unsigned* mkey  = (unsigned*)(region + 35651584);  //  1,600,000
  float*    denom = (float*)(region + 37251584);     //  1,600,000 (contig w/ mkey)
  bf16*     xb    = (bf16*)(region + 38851584);      // [N][256] bf16 = 25,600,000 (end 64,451,584)
  bf16*     eab   = (bf16*)(region + 64451584);      // [6][E][16] bf16 = 6,291,456 (end 70,743,040)
  float*    agg   = out;                             // d_out as fp32 accumulator (phase 1)
  // phase-2 overlay (kvbuf dead)
  bf16*  hbuf     = (bf16*)(region + 0);             // 25,600,000
  float* interw   = (float*)(region + 33554432);     //  1,200,000 (sc/exb slots)
  // phase-3 overlay (hbuf/interw/xb dead)
  bf16*  tmp      = (bf16*)(region + 0);             // [2][N][256] = 51,200,000
  float* logits   = (float*)(region + 51200000);     //    600,000 (end 51,800,000)
  // phase-5
  bf16*  comb     = (bf16*)out;                      // [N][512] bf16 in d_out
  float* combined = (float*)(region + 0);            // [N][256] fp32 (tmp dead; logits above)

  // grids: x = col tiles, y = row tiles (A-tile L2 reuse across x)
  const dim3 gN(2, 391);     // M=50000, NC=256
  const dim3 gQ(12, 391);    // M=50000, NC=1536 (batched q)
  const dim3 gKV(4, 256);    // M=32768, NC=512 (k||v)
  const dim3 gMP2(2, 391, 2);// metapath batch z=0,1
  const dim3 gMP1(2, 391, 1);// metapath batch z=2
  const dim3 gL(1, 391, 3);  // M=50000, NC=128, z=3 meta-paths (logits)

  // ---- phase 0: weight transpose/convert + x->bf16 + eattr->bf16 ----
  tconv_k<<<dim3(8, 8, 6), 256, 0, stream>>>(Wq, Wqt, 256, 256, 256, 256 * 256, 256 * 256);
  tconv_k<<<dim3(10, 8, 6), 256, 0, stream>>>(Wk, Wkvt, 272, 256, 320, 272 * 256, 512 * 320);
  tconv_k<<<dim3(10, 8, 6), 256, 0, stream>>>(Wv, Wkvt + 256 * 320, 272, 256, 320, 272 * 256, 512 * 320);
  tconv_k<<<dim3(8, 8, 6), 256, 0, stream>>>(Wm, Wmt, 256, 256, 256, 256 * 256, 256 * 256);
  tconv_k<<<dim3(48, 8, 1), 256, 0, stream>>>(W_ir1, Wir1t, 1536, 256, 1536, 0, 0);
  tconv_k<<<dim3(16, 8, 1), 256, 0, stream>>>(Wc, Wct, 512, 256, 512, 0, 0);
  tconv_k<<<dim3(8, 8, 3), 256, 0, stream>>>(Wmp, Wmpt, 256, 256, 256, 256 * 256, 256 * 256);
  tconv_k<<<dim3(8, 4, 1), 256, 0, stream>>>(Wa1, Wa1t, 256, 128, 256, 0, 0);
  bkv_k<<<12, 256, 0, stream>>>(bk, bv, bkv);
  cvt_k<<<(NN * 64 + 255) / 256, 256, 0, stream>>>(x, xb, NN * 64);
  cvt_k<<<(RR * EE * FF / 4 + 255) / 256, 256, 0, stream>>>(eattr, eab, RR * EE * FF / 4);

  // ---- phase 1a: ALL q in one GEMM (bf16 A, async staging) -> rel_cat.
  // Slot r is consumed by scores_k(r) BEFORE the Wm GEMM overwrites it. ----
  mm_k<0, 0, 0, bf16><<<gQ, 256, 0, stream>>>(
      xb, nullptr, 256, nullptr, nullptr,
      Wqt, bq, nullptr, rel_cat, 1536, nullptr, NN, 256, 0);

  // ---- phase 1b: per-relation attention ----
  for (int r = 0; r < RR; ++r) {
    const int* src = eidx + (size_t)r * 2 * EE;
    const int* dst = src + EE;
    zero_k<<<391, 256, 0, stream>>>((uint4*)mkey, (2 * NN * NHEAD * 4) / 16);  // mkey+denom
    zero_k<<<2048, 256, 0, stream>>>((uint4*)agg, (NN * HH * 4) / 16);
    // k||v = [xb[src]||eab||0] @ Wkv[r]  (gather reg-staged, NC=512, K=320)
    mm_k<3, 0, 0, bf16><<<gKV, 256, 0, stream>>>(
        xb, nullptr, 0, src, eab + (size_t)r * EE * FF,
        Wkvt + (size_t)r * 512 * KVP, bkv + r * 512, nullptr, kvbuf, 512, nullptr, EE, KVP, 0);
    scores_k<<<EE / 4, 256, 0, stream>>>(rel_cat + r * 256, kvbuf, dst, prior + r * NHEAD, sc, mkey);
    expden_k<<<(EE * NHEAD + 255) / 256, 256, 0, stream>>>(sc, dst, mkey, exb, denom);
    agg_k<<<EE / 4, 256, 0, stream>>>(exb, denom, kvbuf, dst, agg);
    // rel[r] = gelu(agg @ Wm[r] + bm[r]) -> rel_cat slot r (q_r is dead by now)
    mm_k<1, 1, 0, bf16><<<gN, 256, 0, stream>>>(
        agg, nullptr, 256, nullptr, nullptr,
        Wmt + (size_t)r * 256 * 256, bm + r * HH, nullptr,
        rel_cat + r * 256, 1536, nullptr, NN, 256, 0);
  }

  // ---- phase 2: inter-relation chain (consumes rel_cat BEFORE meta overwrites) ----
  mm_k<0, 1, 0, bf16><<<gN, 256, 0, stream>>>(
      rel_cat, nullptr, 1536, nullptr, nullptr,
      Wir1t, b_ir1, nullptr, hbuf, 256, nullptr, NN, 1536, 0);
  interw_k<<<(NN + 3) / 4, 256, 0, stream>>>(hbuf, W_ir2, b_ir2, interw);
  interagg_k<<<NN, 256, 0, stream>>>(interw, rel_cat, comb);

  // ---- phase 3: meta-path chain (z-batched into tmp, then copy to slots) ----
  mm_k<2, 0, 3, bf16><<<gMP2, 256, 0, stream>>>(
      rel_cat, rel_cat, 1536, nullptr, nullptr,
      Wmpt, bmp, nullptr, tmp, 256, nullptr, NN, 256, 0);
  copyslot_k<<<(NN * 32 + 255) / 256, 256, 0, stream>>>(tmp, rel_cat + 2 * 256);
  copyslot_k<<<(NN * 32 + 255) / 256, 256, 0, stream>>>(tmp + (size_t)NN * 256, rel_cat + 4 * 256);
  mm_k<2, 0, 3, bf16><<<gMP1, 256, 0, stream>>>(
      rel_cat, rel_cat, 1536, nullptr, nullptr,
      Wmpt, bmp, nullptr, tmp, 256, nullptr, NN, 256, 2);
  copyslot_k<<<(NN * 32 + 255) / 256, 256, 0, stream>>>(tmp, rel_cat + 1 * 256);

  zero_k<<<147, 256, 0, stream>>>((uint4*)logits, (3 * NN * 4) / 16);
  // logits[z] = sum_i tanh(stacked[z] @ Wa1 + ba1)_i * Wa2_i  (z=3 batched)
  mm_k<0, 0, 1, bf16><<<gL, 256, 0, stream>>>(
      rel_cat, nullptr, 1536, nullptr, nullptr,
      Wa1t, ba1, Wa2, (bf16*)nullptr, 0, logits, NN, 256, 0);
  metafinal_k<<<(NN + 3) / 4, 256, 0, stream>>>(logits, rel_cat, g_meta, b_meta, comb);

  // ---- phase 4: combine + output LN (d_out) ----
  mm_k<0, 1, 0, float><<<gN, 256, 0, stream>>>(
      comb, nullptr, 512, nullptr, nullptr,
      Wct, bc, nullptr, combined, 256, nullptr, NN, 512, 0);
  final_k<<<NN, 256, 0, stream>>>(x, combined, g_out, b_out, out);
}

// Round 5
// 1441.692 us; speedup vs baseline: 1.4043x; 1.4043x over previous
//
#include <hip/hip_runtime.h>
#include <hip/hip_bf16.h>

typedef __hip_bfloat16 bf16;
typedef __attribute__((ext_vector_type(8))) short short8;
typedef __attribute__((ext_vector_type(4))) float f32x4;

#define NN 50000
#define RR 6
#define EE 32768
#define HH 256
#define FF 16
#define NHEAD 8
#define KVP 320   // 272 padded to multiple of 64

struct __align__(8) bf16x4 { bf16 v[4]; };

__device__ __forceinline__ float b2f(bf16 v) { return __bfloat162float(v); }
__device__ __forceinline__ bf16 f2b(float v) { return __float2bfloat16(v); }
__device__ __forceinline__ short f2s(float f) { bf16 b = f2b(f); return __builtin_bit_cast(short, b); }
__device__ __forceinline__ float s2f(short s) { return b2f(__builtin_bit_cast(bf16, s)); }
__device__ __forceinline__ float gelu_f(float x) { return 0.5f * x * (1.0f + erff(x * 0.7071067811865476f)); }

// async global->LDS, 16B per lane (dest = wave-uniform base + lane*16)
__device__ __forceinline__ void gl2lds16(const void* g, void* l) {
  __builtin_amdgcn_global_load_lds(
      (const __attribute__((address_space(1))) unsigned int*)g,
      (__attribute__((address_space(3))) unsigned int*)l, 16, 0, 0);
}

// grid-stride zero fill (16B granules)
__global__ void zero_k(uint4* __restrict__ p, int n16)
{
  const uint4 z = make_uint4(0u, 0u, 0u, 0u);
  for (int i = blockIdx.x * blockDim.x + threadIdx.x; i < n16; i += gridDim.x * blockDim.x)
    p[i] = z;
}

// fp32 -> bf16 elementwise (4 per thread)
__global__ void cvt_k(const float* __restrict__ in, bf16* __restrict__ out, int n4)
{
  const int i = blockIdx.x * 256 + threadIdx.x;
  if (i >= n4) return;
  const float4 f = ((const float4*)in)[i];
  bf16x4 o; o.v[0] = f2b(f.x); o.v[1] = f2b(f.y); o.v[2] = f2b(f.z); o.v[3] = f2b(f.w);
  ((bf16x4*)out)[i] = o;
}

// transpose-convert: in fp32 [K][NC] -> out bf16 [NC][Kp], zero-pad K..Kp.
__global__ void tconv_k(const float* __restrict__ in, bf16* __restrict__ out,
                        int K, int NC, int Kp, long izs, long ozs)
{
  __shared__ float t[32][33];
  in  += (size_t)blockIdx.z * izs;
  out += (size_t)blockIdx.z * ozs;
  const int kb = blockIdx.x * 32, nb = blockIdx.y * 32;
  const int tx = threadIdx.x & 31, ty = threadIdx.x >> 5;  // ty 0..7
  for (int i = ty; i < 32; i += 8) {
    const int k = kb + i, n = nb + tx;
    t[i][tx] = (k < K && n < NC) ? in[(size_t)k * NC + n] : 0.f;
  }
  __syncthreads();
  for (int i = ty; i < 32; i += 8) {
    const int n = nb + i, k = kb + tx;
    if (n < NC && k < Kp) out[(size_t)n * Kp + k] = f2b(t[tx][i]);
  }
}

// build concatenated kv bias: bkv[r][0..255]=bk[r], bkv[r][256..511]=bv[r]
__global__ void bkv_k(const float* __restrict__ bk, const float* __restrict__ bv,
                      float* __restrict__ bkv)
{
  const int i = blockIdx.x * 256 + threadIdx.x;
  if (i >= RR * 512) return;
  const int r = i >> 9, c = i & 511;
  bkv[i] = (c < 256) ? bk[r * 256 + c] : bv[r * 256 + (c - 256)];
}

// copy tmp [N][256] bf16 -> rel_cat slot (ld 1536)
__global__ void copyslot_k(const bf16* __restrict__ tmp, bf16* __restrict__ slot)
{
  const int i = blockIdx.x * 256 + threadIdx.x;  // 8-elem chunk id
  if (i >= NN * 32) return;
  const int n = i >> 5, c = (i & 31) * 8;
  *(short8*)(slot + (size_t)n * 1536 + c) = *(const short8*)(tmp + (size_t)n * 256 + c);
}

// ---------------------------------------------------------------------------
// MFMA GEMM: C[M,NC] = act(A[M,K] @ Bt^T + bias), Bt = [NC][K] bf16 k-contig.
// 128x128 tile, BK=64, 4 waves, each wave 64x64 (4x4 of 16x16x32 MFMA).
// (round-0 proven 1-phase structure; 32KB LDS keeps ~3 blocks/CU -- the
//  64KB double-buffer variant halved residency and was net-neutral.)
// LDS chunk (row, cg) holds global chunk cg ^ (row&7): staging stays
// lane-contiguous (gl2lds16-legal) while fragment reads spread banks.
// ASRC: 0=A bf16 async; 2=PAIR bf16 sum; 3=KV gather (xb bf16 via src +
//       eab bf16 + zero pad); 4=A fp32 scaled by 1/(dnm[row,head]+1e-16)
//       (unnormalized softmax agg -> normalized, fused into staging).
// ZMODE: 0=plain; 1=logits: A = rel_cat + slot3[z]*256, epilogue
//        atomicAdd(logits[z*M+row], sum_col tanh(c+bias[col])*wa2[col]);
//        3=metapath batch: z=blockIdx.z+z0 picks pair slots r1/r2 + B/bias,
//        C += blockIdx.z*M*256.
// ---------------------------------------------------------------------------
template<int ASRC, int ACT, int ZMODE, typename TO>
__global__ __launch_bounds__(256) void mm_k(
    const void* __restrict__ Av, const bf16* __restrict__ A2, int lda,
    const int* __restrict__ src, const bf16* __restrict__ eab,
    const float* __restrict__ dnm,
    const bf16* __restrict__ Bt, const float* __restrict__ bias,
    const float* __restrict__ wa2, TO* __restrict__ C, int ldc,
    float* __restrict__ logits, int M, int K, int z0)
{
  __shared__ short lA[128 * 64];
  __shared__ short lB[128 * 64];
  const int tid = threadIdx.x;
  const int w = tid >> 6, l = tid & 63;
  const int col0 = blockIdx.x << 7;
  const int row0 = blockIdx.y << 7;
  const bf16* Ab = (const bf16*)Av;
  const bf16* A2b = A2;
  const bf16* Btz = Bt;
  const float* biasz = bias;
  TO* Cz = C;
  float* lg = logits;
  if constexpr (ZMODE == 1) {
    const int slots3[3] = {2, 4, 1};
    Ab = (const bf16*)Av + slots3[blockIdx.z] * 256;
    lg = logits + (size_t)blockIdx.z * M;
  } else if constexpr (ZMODE == 3) {
    const int r1s[3] = {2, 4, 1}, r2s[3] = {3, 0, 5};
    const int z = blockIdx.z + z0;
    Ab  = (const bf16*)Av + (size_t)r1s[z] * 256;
    A2b = A2 + (size_t)r2s[z] * 256;
    Btz = Bt + (size_t)z * 256 * K;
    biasz = bias + z * 256;
    Cz = C + (size_t)blockIdx.z * (size_t)M * 256;
  }
  const int wm = (w >> 1) << 6, wn = (w & 1) << 6;
  const int lane15 = l & 15, kq = l >> 4;

  f32x4 acc[4][4] = {};

  for (int k0 = 0; k0 < K; k0 += 64) {
    // stage A tile [128][64] (swizzled chunks)
#pragma unroll
    for (int i = 0; i < 4; ++i) {
      const int idx = (w * 4 + i) * 64 + l;        // 0..1023 16B chunks
      const int row = idx >> 3, cg = idx & 7;
      const int scg = cg ^ (row & 7);
      const int r = min(row0 + row, M - 1);
      const int kc = k0 + scg * 8;
      if constexpr (ASRC == 0) {
        gl2lds16(Ab + (size_t)r * lda + kc, &lA[idx * 8]);
      } else if constexpr (ASRC == 2) {
        const short8 u  = *(const short8*)(Ab  + (size_t)r * lda + kc);
        const short8 v2 = *(const short8*)(A2b + (size_t)r * lda + kc);
        short8 s;
#pragma unroll
        for (int j = 0; j < 8; ++j) s[j] = f2s(s2f(u[j]) + s2f(v2[j]));
        *(short8*)&lA[idx * 8] = s;
      } else if constexpr (ASRC == 3) {  // kv gather: xb bf16 | eab bf16 | pad
        short8 s;
        if (kc < HH) {
          s = *(const short8*)((const bf16*)Av + (size_t)src[r] * HH + kc);
        } else if (kc < HH + FF) {
          s = *(const short8*)(eab + (size_t)r * FF + (kc - HH));
        } else {
#pragma unroll
          for (int j = 0; j < 8; ++j) s[j] = 0;
        }
        *(short8*)&lA[idx * 8] = s;
      } else {  // ASRC == 4: fp32 agg scaled by 1/(denom+1e-16), chunk in one head
        const float* p = (const float*)Av + (size_t)r * lda + kc;
        const float4 f0 = *(const float4*)p;
        const float4 f1 = *(const float4*)(p + 4);
        const float iv = 1.0f / (dnm[r * NHEAD + (kc >> 5)] + 1e-16f);
        short8 s;
        s[0] = f2s(f0.x * iv); s[1] = f2s(f0.y * iv); s[2] = f2s(f0.z * iv); s[3] = f2s(f0.w * iv);
        s[4] = f2s(f1.x * iv); s[5] = f2s(f1.y * iv); s[6] = f2s(f1.z * iv); s[7] = f2s(f1.w * iv);
        *(short8*)&lA[idx * 8] = s;
      }
    }
    // stage B tile [128][64] (swizzled, async; block's 128 cols always in range)
#pragma unroll
    for (int i = 0; i < 4; ++i) {
      const int idx = (w * 4 + i) * 64 + l;
      const int row = idx >> 3, cg = idx & 7;
      const int scg = cg ^ (row & 7);
      gl2lds16(Btz + (size_t)(col0 + row) * K + k0 + scg * 8, &lB[idx * 8]);
    }
    __syncthreads();
#pragma unroll
    for (int kk = 0; kk < 64; kk += 32) {
      short8 af[4], bfr[4];
#pragma unroll
      for (int t = 0; t < 4; ++t) {
        const int ra = wm + t * 16 + lane15;
        const int ca = ((kk >> 3) + kq) ^ (ra & 7);
        af[t] = *(const short8*)&lA[ra * 64 + ca * 8];
        const int rb = wn + t * 16 + lane15;
        const int cb = ((kk >> 3) + kq) ^ (rb & 7);
        bfr[t] = *(const short8*)&lB[rb * 64 + cb * 8];
      }
#pragma unroll
      for (int ti = 0; ti < 4; ++ti)
#pragma unroll
        for (int tj = 0; tj < 4; ++tj)
          acc[ti][tj] = __builtin_amdgcn_mfma_f32_16x16x32_bf16(af[ti], bfr[tj], acc[ti][tj], 0, 0, 0);
    }
    __syncthreads();
  }

  if constexpr (ZMODE != 1) {
    // C layout: col = lane&15, row = (lane>>4)*4 + reg  [m89-verified]
#pragma unroll
    for (int ti = 0; ti < 4; ++ti) {
#pragma unroll
      for (int reg = 0; reg < 4; ++reg) {
        const int row = row0 + wm + ti * 16 + kq * 4 + reg;
        if (row >= M) continue;
#pragma unroll
        for (int tj = 0; tj < 4; ++tj) {
          const int col = col0 + wn + tj * 16 + lane15;
          float v = acc[ti][tj][reg] + biasz[col];
          if constexpr (ACT == 1) v = gelu_f(v);
          if constexpr (sizeof(TO) == 2) Cz[(size_t)row * ldc + col] = (TO)f2b(v);
          else                           Cz[(size_t)row * ldc + col] = (TO)v;
        }
      }
    }
  } else {
#pragma unroll
    for (int ti = 0; ti < 4; ++ti) {
#pragma unroll
      for (int reg = 0; reg < 4; ++reg) {
        float part = 0.f;
#pragma unroll
        for (int tj = 0; tj < 4; ++tj) {
          const int col = col0 + wn + tj * 16 + lane15;
          part += tanhf(acc[ti][tj][reg] + biasz[col]) * wa2[col];
        }
#pragma unroll
        for (int off = 8; off > 0; off >>= 1) part += __shfl_xor(part, off, 64);
        const int row = row0 + wm + ti * 16 + kq * 4 + reg;
        if (lane15 == 0 && row < M) atomicAdd(&lg[row], part);
      }
    }
  }
}

// ---------------------------------------------------------------------------
// Fused edge pass: per edge e (one 256-thread block):
//   s_h   = (sum_t q[dst][h*32+t] * k[e][h*32+t]) * scale * prior[h]
//   ex_h  = exp(s_h)                      (softmax is shift-invariant: no max)
//   denom[dst,h] += ex_h ;  agg[dst, t] += ex_h * v[e][t]   (contig atomics)
// q lives in rel_cat (ld 1536, slot r); k/v in kv [E][512].
// Normalization by denom happens later in the Wm GEMM staging (ASRC=4).
// ---------------------------------------------------------------------------
__global__ void edge_k(const bf16* __restrict__ q, const bf16* __restrict__ kv,
                       const int* __restrict__ dst_idx, const float* __restrict__ prior_r,
                       float* __restrict__ denom, float* __restrict__ agg)
{
  const int e = blockIdx.x, t = threadIdx.x;
  const int dst = dst_idx[e];
  const int h = t >> 5;
  float p = b2f(q[(size_t)dst * 1536 + t]) * b2f(kv[(size_t)e * 512 + t]);
#pragma unroll
  for (int off = 16; off > 0; off >>= 1) p += __shfl_down(p, off, 32);
  const float s = __shfl(p, 0, 32);   // broadcast head sum within 32-group
  const float ex = expf(s * 0.1767766952966369f * prior_r[h]);
  if ((t & 31) == 0) atomicAdd(&denom[dst * NHEAD + h], ex);
  atomicAdd(&agg[(size_t)dst * HH + t], ex * b2f(kv[(size_t)e * 512 + 256 + t]));
}

// ---------------------------------------------------------------------------
// inter-relation softmax weights; one wave per node
// ---------------------------------------------------------------------------
__global__ void interw_k(const bf16* __restrict__ h, const float* __restrict__ W2,
                         const float* __restrict__ b2, float* __restrict__ interw)
{
  const int wv = threadIdx.x >> 6, ln = threadIdx.x & 63;
  const int n = blockIdx.x * 4 + wv;
  if (n >= NN) return;
  float a[6] = {0.f, 0.f, 0.f, 0.f, 0.f, 0.f};
#pragma unroll
  for (int kq = 0; kq < 4; ++kq) {
    const int k = ln + (kq << 6);
    const float hv = b2f(h[(size_t)n * HH + k]);
#pragma unroll
    for (int j = 0; j < 6; ++j) a[j] += hv * W2[k * 6 + j];
  }
#pragma unroll
  for (int j = 0; j < 6; ++j) {
#pragma unroll
    for (int off = 32; off > 0; off >>= 1) a[j] += __shfl_down(a[j], off, 64);
  }
  if (ln == 0) {
    float lg[6], e[6], mx = -1e30f, s = 0.f;
#pragma unroll
    for (int j = 0; j < 6; ++j) { lg[j] = a[j] + b2[j]; mx = fmaxf(mx, lg[j]); }
#pragma unroll
    for (int j = 0; j < 6; ++j) { e[j] = expf(lg[j] - mx); s += e[j]; }
    const float inv = 1.0f / s;
#pragma unroll
    for (int j = 0; j < 6; ++j) interw[(size_t)n * 6 + j] = e[j] * inv;
  }
}

// rel_cat layout: [N][R*256]
__global__ void interagg_k(const float* __restrict__ interw, const bf16* __restrict__ rel_cat,
                           bf16* __restrict__ comb)
{
  const int n = blockIdx.x, t = threadIdx.x;
  float acc = 0.f;
#pragma unroll
  for (int r = 0; r < 6; ++r)
    acc += interw[(size_t)n * 6 + r] * b2f(rel_cat[(size_t)n * 1536 + r * 256 + t]);
  comb[(size_t)n * 512 + t] = f2b(acc);
}

// ---------------------------------------------------------------------------
// meta final: softmax(logits[3]) -> weighted sum of stacked -> LN -> comb[:,256:]
// stacked[p] lives in rel_cat slots {2,4,1} (ld 1536); logits = [3][N] fp32
// ---------------------------------------------------------------------------
__global__ void metafinal_k(const float* __restrict__ logits, const bf16* __restrict__ rel_cat,
                            const float* __restrict__ gmeta, const float* __restrict__ bmeta,
                            bf16* __restrict__ comb)
{
  const int wv = threadIdx.x >> 6, ln = threadIdx.x & 63;
  const int n = blockIdx.x * 4 + wv;
  if (n >= NN) return;
  const float l0 = logits[n], l1 = logits[NN + n], l2 = logits[2 * NN + n];
  const float mx = fmaxf(l0, fmaxf(l1, l2));
  const float e0 = expf(l0 - mx), e1 = expf(l1 - mx), e2 = expf(l2 - mx);
  const float inv = 1.0f / (e0 + e1 + e2);
  const float a0 = e0 * inv, a1 = e1 * inv, a2 = e2 * inv;
  const size_t base = (size_t)n * 1536;
  float pre[4], s = 0.f, s2 = 0.f;
#pragma unroll
  for (int q4 = 0; q4 < 4; ++q4) {
    const int j = ln + (q4 << 6);
    const float v = a0 * b2f(rel_cat[base + 2 * 256 + j])
                  + a1 * b2f(rel_cat[base + 4 * 256 + j])
                  + a2 * b2f(rel_cat[base + 1 * 256 + j]);
    pre[q4] = v; s += v; s2 += v * v;
  }
#pragma unroll
  for (int off = 32; off > 0; off >>= 1) { s += __shfl_down(s, off, 64); s2 += __shfl_down(s2, off, 64); }
  s = __shfl(s, 0, 64); s2 = __shfl(s2, 0, 64);
  const float mu = s * (1.0f / 256.0f);
  const float var = s2 * (1.0f / 256.0f) - mu * mu;
  const float rs = rsqrtf(var + 1e-5f);
#pragma unroll
  for (int q4 = 0; q4 < 4; ++q4) {
    const int j = ln + (q4 << 6);
    comb[(size_t)n * 512 + 256 + j] = f2b((pre[q4] - mu) * rs * gmeta[j] + bmeta[j]);
  }
}

// final: out = LN(x + combined)
__global__ void final_k(const float* __restrict__ x, const float* __restrict__ combined,
                        const float* __restrict__ g, const float* __restrict__ b,
                        float* __restrict__ out)
{
  __shared__ float sred[8];
  const int n = blockIdx.x, t = threadIdx.x;
  const float v = x[(size_t)n * HH + t] + combined[(size_t)n * HH + t];
  float s = v, s2 = v * v;
#pragma unroll
  for (int off = 32; off > 0; off >>= 1) { s += __shfl_down(s, off, 64); s2 += __shfl_down(s2, off, 64); }
  const int wv = t >> 6;
  if ((t & 63) == 0) { sred[wv] = s; sred[4 + wv] = s2; }
  __syncthreads();
  const float st = sred[0] + sred[1] + sred[2] + sred[3];
  const float st2 = sred[4] + sred[5] + sred[6] + sred[7];
  const float mu = st * (1.0f / 256.0f);
  const float var = st2 * (1.0f / 256.0f) - mu * mu;
  const float rs = rsqrtf(var + 1e-5f);
  out[(size_t)n * HH + t] = (v - mu) * rs * g[t] + b[t];
}

// ---------------------------------------------------------------------------
extern "C" void kernel_launch(void* const* d_in, const int* in_sizes, int n_in,
                              void* d_out, int out_size, void* d_ws, size_t ws_size,
                              hipStream_t stream)
{
  const float* x      = (const float*)d_in[0];
  const int*   eidx   = (const int*)d_in[1];
  const float* eattr  = (const float*)d_in[2];
  const float* Wq     = (const float*)d_in[3];
  const float* bq     = (const float*)d_in[4];
  const float* Wk     = (const float*)d_in[5];
  const float* bk     = (const float*)d_in[6];
  const float* Wv     = (const float*)d_in[7];
  const float* bv     = (const float*)d_in[8];
  const float* prior  = (const float*)d_in[9];
  const float* Wm     = (const float*)d_in[10];
  const float* bm     = (const float*)d_in[11];
  const float* W_ir1  = (const float*)d_in[12];
  const float* b_ir1  = (const float*)d_in[13];
  const float* W_ir2  = (const float*)d_in[14];
  const float* b_ir2  = (const float*)d_in[15];
  const float* Wmp    = (const float*)d_in[16];
  const float* bmp    = (const float*)d_in[17];
  const float* Wa1    = (const float*)d_in[18];
  const float* ba1    = (const float*)d_in[19];
  const float* Wa2    = (const float*)d_in[20];
  const float* g_meta = (const float*)d_in[21];
  const float* b_meta = (const float*)d_in[22];
  const float* Wc     = (const float*)d_in[23];
  const float* bc     = (const float*)d_in[24];
  const float* g_out  = (const float*)d_in[25];
  const float* b_out  = (const float*)d_in[26];
  float* out = (float*)d_out;

  // ---- workspace layout: PEAK ~229.4 MB (< 235.88 MB proven safe) ----
  char* ws = (char*)d_ws;
  bf16* rel_cat = (bf16*)ws;                         // [N][1536] bf16 = 153,600,000
  char* W0 = ws + 153600000;                         // weights: 5,058,560
  bf16*  Wqt   = (bf16*)(W0 + 0);          // [1536][256]   (6 relations stacked on NC)
  bf16*  Wkvt  = (bf16*)(W0 + 786432);     // [6][512][320] (k rows 0..255, v rows 256..511)
  bf16*  Wmt   = (bf16*)(W0 + 2752512);    // [6][256][256]
  bf16*  Wir1t = (bf16*)(W0 + 3538944);    // [256][1536]
  bf16*  Wct   = (bf16*)(W0 + 4325376);    // [256][512]
  bf16*  Wmpt  = (bf16*)(W0 + 4587520);    // [3][256][256]
  bf16*  Wa1t  = (bf16*)(W0 + 4980736);    // [128][256]
  float* bkv   = (float*)(W0 + 5046272);   // [6][512] fp32 (end 5,058,560)
  char* region = ws + 158658560;
  // phase-1 views
  bf16*     kvbuf = (bf16*)(region + 0);             // [E][512] bf16 = 33,554,432
  float*    denom = (float*)(region + 33554432);     //  1,600,000
  bf16*     xb    = (bf16*)(region + 38851584);      // [N][256] bf16 = 25,600,000 (end 64,451,584)
  bf16*     eab   = (bf16*)(region + 64451584);      // [6][E][16] bf16 = 6,291,456 (end 70,743,040)
  float*    agg   = out;                             // d_out as fp32 accumulator (phase 1)
  // phase-2 overlay (kvbuf dead)
  bf16*  hbuf     = (bf16*)(region + 0);             // 25,600,000
  float* interw   = (float*)(region + 33554432);     //  1,200,000 (denom dead)
  // phase-3 overlay (hbuf/interw/xb dead)
  bf16*  tmp      = (bf16*)(region + 0);             // [2][N][256] = 51,200,000
  float* logits   = (float*)(region + 51200000);     //    600,000 (end 51,800,000)
  // phase-5
  bf16*  comb     = (bf16*)out;                      // [N][512] bf16 in d_out
  float* combined = (float*)(region + 0);            // [N][256] fp32 (tmp dead; logits above)

  // grids: x = col tiles, y = row tiles (A-tile L2 reuse across x)
  const dim3 gN(2, 391);     // M=50000, NC=256
  const dim3 gQ(12, 391);    // M=50000, NC=1536 (batched q)
  const dim3 gKV(4, 256);    // M=32768, NC=512 (k||v)
  const dim3 gMP2(2, 391, 2);// metapath batch z=0,1
  const dim3 gMP1(2, 391, 1);// metapath batch z=2
  const dim3 gL(1, 391, 3);  // M=50000, NC=128, z=3 meta-paths (logits)

  // ---- phase 0: weight transpose/convert + x->bf16 + eattr->bf16 ----
  tconv_k<<<dim3(8, 8, 6), 256, 0, stream>>>(Wq, Wqt, 256, 256, 256, 256 * 256, 256 * 256);
  tconv_k<<<dim3(10, 8, 6), 256, 0, stream>>>(Wk, Wkvt, 272, 256, 320, 272 * 256, 512 * 320);
  tconv_k<<<dim3(10, 8, 6), 256, 0, stream>>>(Wv, Wkvt + 256 * 320, 272, 256, 320, 272 * 256, 512 * 320);
  tconv_k<<<dim3(8, 8, 6), 256, 0, stream>>>(Wm, Wmt, 256, 256, 256, 256 * 256, 256 * 256);
  tconv_k<<<dim3(48, 8, 1), 256, 0, stream>>>(W_ir1, Wir1t, 1536, 256, 1536, 0, 0);
  tconv_k<<<dim3(16, 8, 1), 256, 0, stream>>>(Wc, Wct, 512, 256, 512, 0, 0);
  tconv_k<<<dim3(8, 8, 3), 256, 0, stream>>>(Wmp, Wmpt, 256, 256, 256, 256 * 256, 256 * 256);
  tconv_k<<<dim3(8, 4, 1), 256, 0, stream>>>(Wa1, Wa1t, 256, 128, 256, 0, 0);
  bkv_k<<<12, 256, 0, stream>>>(bk, bv, bkv);
  cvt_k<<<(NN * 64 + 255) / 256, 256, 0, stream>>>(x, xb, NN * 64);
  cvt_k<<<(RR * EE * FF / 4 + 255) / 256, 256, 0, stream>>>(eattr, eab, RR * EE * FF / 4);

  // ---- phase 1a: ALL q in one GEMM (bf16 A, pure async staging) -> rel_cat.
  // Slot r is consumed by edge_k(r) BEFORE the Wm GEMM overwrites it. ----
  mm_k<0, 0, 0, bf16><<<gQ, 256, 0, stream>>>(
      xb, nullptr, 256, nullptr, nullptr, nullptr,
      Wqt, bq, nullptr, rel_cat, 1536, nullptr, NN, 256, 0);

  // ---- phase 1b: per-relation attention (fused edge pass, no segment-max:
  // softmax is shift-invariant; scores are O(1) so exp() cannot overflow) ----
  for (int r = 0; r < RR; ++r) {
    const int* src = eidx + (size_t)r * 2 * EE;
    const int* dst = src + EE;
    zero_k<<<98, 256, 0, stream>>>((uint4*)denom, (NN * NHEAD * 4) / 16);
    zero_k<<<2048, 256, 0, stream>>>((uint4*)agg, (NN * HH * 4) / 16);
    // k||v = [xb[src]||eab||0] @ Wkv[r]  (gather in staging, NC=512, K=320)
    mm_k<3, 0, 0, bf16><<<gKV, 256, 0, stream>>>(
        xb, nullptr, 0, src, eab + (size_t)r * EE * FF, nullptr,
        Wkvt + (size_t)r * 512 * KVP, bkv + r * 512, nullptr, kvbuf, 512, nullptr, EE, KVP, 0);
    // fused scores+exp+aggregate (unnormalized): denom & agg accumulate
    edge_k<<<EE, 256, 0, stream>>>(rel_cat + r * 256, kvbuf, dst, prior + r * NHEAD, denom, agg);
    // rel[r] = gelu((agg/denom) @ Wm[r] + bm[r]) -> rel_cat slot r
    mm_k<4, 1, 0, bf16><<<gN, 256, 0, stream>>>(
        agg, nullptr, 256, nullptr, nullptr, denom,
        Wmt + (size_t)r * 256 * 256, bm + r * HH, nullptr,
        rel_cat + r * 256, 1536, nullptr, NN, 256, 0);
  }

  // ---- phase 2: inter-relation chain (consumes rel_cat BEFORE meta overwrites) ----
  mm_k<0, 1, 0, bf16><<<gN, 256, 0, stream>>>(
      rel_cat, nullptr, 1536, nullptr, nullptr, nullptr,
      Wir1t, b_ir1, nullptr, hbuf, 256, nullptr, NN, 1536, 0);
  interw_k<<<(NN + 3) / 4, 256, 0, stream>>>(hbuf, W_ir2, b_ir2, interw);
  interagg_k<<<NN, 256, 0, stream>>>(interw, rel_cat, comb);

  // ---- phase 3: meta-path chain (z-batched into tmp, then copy to slots) ----
  mm_k<2, 0, 3, bf16><<<gMP2, 256, 0, stream>>>(
      rel_cat, rel_cat, 1536, nullptr, nullptr, nullptr,
      Wmpt, bmp, nullptr, tmp, 256, nullptr, NN, 256, 0);
  copyslot_k<<<(NN * 32 + 255) / 256, 256, 0, stream>>>(tmp, rel_cat + 2 * 256);
  copyslot_k<<<(NN * 32 + 255) / 256, 256, 0, stream>>>(tmp + (size_t)NN * 256, rel_cat + 4 * 256);
  mm_k<2, 0, 3, bf16><<<gMP1, 256, 0, stream>>>(
      rel_cat, rel_cat, 1536, nullptr, nullptr, nullptr,
      Wmpt, bmp, nullptr, tmp, 256, nullptr, NN, 256, 2);
  copyslot_k<<<(NN * 32 + 255) / 256, 256, 0, stream>>>(tmp, rel_cat + 1 * 256);

  zero_k<<<147, 256, 0, stream>>>((uint4*)logits, (3 * NN * 4) / 16);
  // logits[z] = sum_i tanh(stacked[z] @ Wa1 + ba1)_i * Wa2_i  (z=3 batched)
  mm_k<0, 0, 1, bf16><<<gL, 256, 0, stream>>>(
      rel_cat, nullptr, 1536, nullptr, nullptr, nullptr,
      Wa1t, ba1, Wa2, (bf16*)nullptr, 0, logits, NN, 256, 0);
  metafinal_k<<<(NN + 3) / 4, 256, 0, stream>>>(logits, rel_cat, g_meta, b_meta, comb);

  // ---- phase 4: combine + output LN (d_out) ----
  mm_k<0, 1, 0, float><<<gN, 256, 0, stream>>>(
      comb, nullptr, 512, nullptr, nullptr, nullptr,
      Wct, bc, nullptr, combined, 256, nullptr, NN, 512, 0);
  final_k<<<NN, 256, 0, stream>>>(x, combined, g_out, b_out, out);
}